// Round 5
// baseline (332.443 us; speedup 1.0000x reference)
//
#include <hip/hip_runtime.h>
#include <cstdint>

#define N_EDGES 12288
#define ROWLEN  2432      // 19*128 floats per edge
#define CAP     2048      // per-system bucket capacity (buckets avg 768)

typedef __bf16 bf16;
typedef __bf16 bf16x8 __attribute__((ext_vector_type(8)));
typedef float  f32x4  __attribute__((ext_vector_type(4)));

#define ELEMS0 (640*640)
#define ELEMS1 (1024*1024)
#define ELEMS2 (768*768)

// ws byte offsets (no xb buffer: A is cast f32->bf16 inside the GEMM)
#define WS_IDX_OFF   1024
#define WS_BIAS_OFF  (WS_IDX_OFF + 16*CAP*4)                 // 132096
#define WS_W_OFF     (WS_BIAS_OFF + 16*640*4)                // 173056
#define WZ_ELEMS     ((size_t)16*(ELEMS0+ELEMS1+ELEMS2))     // 32.77M bf16

// After the SO(2) "hat" fold every branch is a square GEMM with K == N.
template<int B> struct Cfg;
template<> struct Cfg<0> { static constexpr int K=640,  KS=640, XOFF=0,    NT=5;
                           static constexpr size_t WOFF=0; };
template<> struct Cfg<1> { static constexpr int K=1024, KS=512, XOFF=640,  NT=8;
                           static constexpr size_t WOFF=(size_t)16*ELEMS0; };
template<> struct Cfg<2> { static constexpr int K=768,  KS=384, XOFF=1664, NT=6;
                           static constexpr size_t WOFF=(size_t)16*ELEMS0+(size_t)16*ELEMS1; };

__device__ __forceinline__ void async_copy16(const void* g, void* l) {
  // global -> LDS direct copy, 16B/lane; LDS dest = wave-uniform base + lane*16.
  auto gp = reinterpret_cast<const __attribute__((address_space(1))) unsigned int*>(
      reinterpret_cast<uintptr_t>(g));
  auto lp = reinterpret_cast<__attribute__((address_space(3))) unsigned int*>(
      (unsigned int)reinterpret_cast<uintptr_t>(l));
  __builtin_amdgcn_global_load_lds(gp, lp, 16, 0, 0);
}

// ---------------- bucketing: LDS histogram, 16 global atomics per block ------
__global__ void bucket_kernel(const int* __restrict__ eb, int* __restrict__ counts,
                              int* __restrict__ idxb) {
  __shared__ int hcnt[16], hbase[16];
  int tid = threadIdx.x;
  int t = blockIdx.x * 256 + tid;
  if (tid < 16) hcnt[tid] = 0;
  __syncthreads();
  int s = -1, lp = 0;
  if (t < N_EDGES) { s = eb[t]; lp = atomicAdd(&hcnt[s], 1); }
  __syncthreads();
  if (tid < 16) hbase[tid] = atomicAdd(counts + tid, hcnt[tid]);
  __syncthreads();
  if (s >= 0) { int p = hbase[s] + lp; if (p < CAP) idxb[s * CAP + p] = t; }
}

// ---------------- mixed bias ----------------
__global__ void bias_kernel(const float* __restrict__ ce, const float* __restrict__ b0,
                            float* __restrict__ bias) {
  int t = blockIdx.x * 256 + threadIdx.x;   // 0..10239
  int s = t / 640, c = t - s * 640;
  float a = 0.f;
#pragma unroll
  for (int e = 0; e < 8; ++e) a += ce[s * 8 + e] * b0[e * 640 + c];
  bias[t] = a;
}

// ---------------- weight mixing + hat fold + swizzle + bf16 cast ----------------
// dst layout per (branch, system): [kblk][chunk128][kgrp:4][n:128][k8:8] bf16.
template<int B>
__device__ __forceinline__ void mix_body(const float* __restrict__ Wsrc,
                                         const float* ce_s,
                                         unsigned short* __restrict__ Wz, int pos) {
  constexpr int N = Cfg<B>::K, KS = Cfg<B>::KS, NT = N / 128, HALF = N / 2;
  constexpr int SRC_STRIDE = KS * N;
  constexpr size_t DST_STRIDE = (size_t)Cfg<B>::K * N;
  int nn = pos & 127, kgrp = (pos >> 7) & 3, rest = pos >> 9;
  int nt = rest % NT, kblk = rest / NT;
  int i0 = kblk * 32 + kgrp * 8;
  int c  = nt * 128 + nn;
  int si = i0, sc = c; float sg = 1.f;
  if (B > 0 && i0 >= KS) {                      // lower half of hat: [-W2 | W1]
    si = i0 - KS;
    if (c < HALF) { sc = c + HALF; sg = -1.f; } else { sc = c - HALF; }
  }
  float w[8][8];
  const float* p0 = Wsrc + (size_t)si * N + sc;
#pragma unroll
  for (int e = 0; e < 8; ++e) {
    const float* p = p0 + (size_t)e * SRC_STRIDE;
#pragma unroll
    for (int j = 0; j < 8; ++j)
      w[e][j] = sg * p[(size_t)j * N];   // plain loads: hat-fold re-read hits LLC
  }
  unsigned short* db = Wz + Cfg<B>::WOFF + (size_t)pos * 8;
#pragma unroll
  for (int s = 0; s < 16; ++s) {
    float a[8] = {0, 0, 0, 0, 0, 0, 0, 0};
#pragma unroll
    for (int e = 0; e < 8; ++e) {
      float cc = ce_s[s * 8 + e];
#pragma unroll
      for (int j = 0; j < 8; ++j) a[j] += cc * w[e][j];
    }
    bf16x8 v;
#pragma unroll
    for (int j = 0; j < 8; ++j) v[j] = (bf16)a[j];
    *(bf16x8*)(db + s * DST_STRIDE) = v;
  }
}

__global__ __launch_bounds__(256) void mix_all(const float* __restrict__ W0,
                                               const float* __restrict__ W1,
                                               const float* __restrict__ W2,
                                               const float* __restrict__ ce,
                                               unsigned short* __restrict__ Wz) {
  __shared__ float ce_s[128];
  int tid = threadIdx.x;
  if (tid < 128) ce_s[tid] = ce[tid];
  __syncthreads();
  int bx = blockIdx.x;
  if (bx < 200)      mix_body<0>(W0, ce_s, Wz, bx * 256 + tid);
  else if (bx < 712) mix_body<1>(W1, ce_s, Wz, (bx - 200) * 256 + tid);
  else               mix_body<2>(W2, ce_s, Wz, (bx - 712) * 256 + tid);
}

// ---------------- grouped GEMM: 256x256 tile, 8 waves, counted-vmcnt pipeline -
// M=256 halves the Wz re-read volume (LLC data-motion was the measured limit:
// round 3/4 moved ~917 MB logical in 130us = 7 TB/s, schedule-insensitive).
// 8 waves as 4m x 2n; each wave owns 64x128 -> acc[4][8]=128 VGPR (unchanged).
// __launch_bounds__(512,2) -> 256 regs/wave: NO spill (round-1 lesson: the
// spill came from waves/EU=4 capping at 128 regs, not from 512 threads).
// 1 block/CU now, so the counted-vmcnt pipeline (loads in flight across
// raw s_barriers, never vmcnt(0) in-loop) is load-bearing: there is no
// second block to hide the barrier drain behind.
template<int B>
__device__ __forceinline__ void gemm_body(
    const float* __restrict__ x, const char* __restrict__ zeros,
    const unsigned short* __restrict__ Wz,
    const int* __restrict__ counts, const int* __restrict__ idxb,
    const float* __restrict__ bias, float* __restrict__ out,
    int s, int mt, int nt2, char* sm, int* eidx)
{
  constexpr int K = Cfg<B>::K, NT = Cfg<B>::NT, KB = K / 32, XOFF = Cfg<B>::XOFF;
  int cnt = counts[s];
  int m0 = mt * 256;
  if (m0 >= cnt) return;
  int tid = threadIdx.x;
  if (tid < 256) eidx[tid] = (m0 + tid < cnt) ? idxb[s * CAP + m0 + tid] : -1;
  __syncthreads();
  // LDS: A bufs 2x16KB ([kq:4][row:256] 16B chunks), B bufs 3x16KB. Total 80KB.
  char* Acur = sm;          char* Anxt = sm + 16384;
  char* Bc = sm + 32768;    char* Bm = sm + 49152;    char* Bn = sm + 65536;
  int wv = tid >> 6, ln = tid & 63;
  int wm = wv >> 1, wn = wv & 1;          // 4m x 2n waves, each owns 64x128 output
  int kq = ln >> 4, lm = ln & 15;
  int c0 = nt2 * 2;
  // A source: two threads per row; h selects k-half [h*16, h*16+16) of the 32-k tile
  int r_a = tid >> 1, h = tid & 1;
  const char* arow; int kinc;
  { int e = eidx[r_a];
    if (e >= 0) { arow = (const char*)(x + (size_t)e * ROWLEN + XOFF); kinc = 128; }
    else        { arow = zeros; kinc = 0; } }
  const unsigned short* wb = Wz + Cfg<B>::WOFF + (size_t)s * K * K;

  f32x4 sreg[4];                                   // staged A (16 f32)
  auto loadA = [&](int kb) {                       // issue early (T14 split)
    const char* p = arow + (size_t)kb * kinc + h * 64;
#pragma unroll
    for (int i = 0; i < 4; ++i) sreg[i] = *(const f32x4*)(p + i * 16);
  };
  auto writeA = [&](char* dst) {                   // cvt + ds_write late
#pragma unroll
    for (int c = 0; c < 2; ++c) {
      bf16x8 v;
#pragma unroll
      for (int j = 0; j < 8; ++j) v[j] = (bf16)sreg[c * 2 + (j >> 2)][j & 3];
      *(bf16x8*)(dst + ((2 * h + c) * 256 + r_a) * 16) = v;   // chunk (kq=2h+c, row)
    }
  };
  auto stageB = [&](int kb, char* dst) {
    const unsigned short* base = wb + (size_t)kb * (NT * 4096);
#pragma unroll
    for (int i = 0; i < 2; ++i) {
      int c = i * 512 + tid;                       // 1024 16B chunks per buf
      int ck = c0 + (c >> 9); if (ck > NT - 1) ck = NT - 1;   // clamp (dup, discarded)
      async_copy16(base + (size_t)ck * 4096 + (c & 511) * 8,
                   dst + (i * 512 + wv * 64) * 16);
    }
  };

  f32x4 acc[4][8];
#pragma unroll
  for (int i = 0; i < 4; ++i)
#pragma unroll
    for (int j = 0; j < 8; ++j) {
      acc[i][j][0] = 0.f; acc[i][j][1] = 0.f; acc[i][j][2] = 0.f; acc[i][j][3] = 0.f;
    }

  // Prologue: establish invariant for iter 0:
  //   Acur = A(0) (ds-written), Bc = B(0) (landed),
  //   Bm = B(1) in flight, sreg = A(1) in flight.
  loadA(0);                    // issued first -> retired by writeA's auto-wait
  stageB(0, Bc);
  writeA(Acur);                // compiler waits vmcnt for sreg, then ds_writes
  asm volatile("s_waitcnt vmcnt(0)" ::: "memory");   // B(0) landed (one-time drain)
  stageB(1, Bm);
  loadA(1);
  asm volatile("s_waitcnt lgkmcnt(0)" ::: "memory"); // own A(0) ds_writes done
  __builtin_amdgcn_s_barrier();
  __builtin_amdgcn_sched_barrier(0);

#pragma unroll 1
  for (int kb = 0; kb < KB; ++kb) {
    if (kb + 2 < KB) stageB(kb + 2, Bn);          // prefetch depth-2
    bf16x8 af[4], bq[8];
#pragma unroll
    for (int mi = 0; mi < 4; ++mi)
      af[mi] = *(const bf16x8*)(Acur + kq * 4096 + (wm * 64 + mi * 16 + lm) * 16);
#pragma unroll
    for (int ni = 0; ni < 8; ++ni)
      bq[ni] = *(const bf16x8*)(Bc + wn * 8192 + kq * 2048 + (ni * 16 + lm) * 16);
    __builtin_amdgcn_s_setprio(1);
#pragma unroll
    for (int mi = 0; mi < 4; ++mi)
#pragma unroll
      for (int ni = 0; ni < 8; ++ni)
        acc[mi][ni] = __builtin_amdgcn_mfma_f32_16x16x32_bf16(af[mi], bq[ni], acc[mi][ni], 0, 0, 0);
    __builtin_amdgcn_s_setprio(0);
    if (kb + 1 < KB) {
      writeA(Anxt);            // auto vmcnt wait retires loadA(kb+1) AND B(kb+1)
      if (kb + 2 < KB) loadA(kb + 2);             // refill sreg for next writeA
    }
    asm volatile("s_waitcnt lgkmcnt(0)" ::: "memory");  // own ds_writes visible
    __builtin_amdgcn_s_barrier();                 // raw: vmcnt stays nonzero
    __builtin_amdgcn_sched_barrier(0);
    char* t = Acur; Acur = Anxt; Anxt = t;        // rotate buffers
    char* tb = Bc; Bc = Bm; Bm = Bn; Bn = tb;
  }
  // epilogue: C/D layout col=lane&15, row=(lane>>4)*4+reg
  int cc = c0 + wn;
  if (cc >= NT) return;
  float bv[8] = {0, 0, 0, 0, 0, 0, 0, 0};
  if (B == 0) {
#pragma unroll
    for (int ni = 0; ni < 8; ++ni)
      bv[ni] = bias[s * 640 + cc * 128 + ni * 16 + lm];
  }
#pragma unroll
  for (int mi = 0; mi < 4; ++mi) {
#pragma unroll
    for (int r = 0; r < 4; ++r) {
      int row = wm * 64 + mi * 16 + kq * 4 + r;
      int e = eidx[row];
      if (e < 0) continue;
      float* po = out + (size_t)e * ROWLEN + XOFF + cc * 128 + lm;
#pragma unroll
      for (int ni = 0; ni < 8; ++ni) po[ni * 16] = acc[mi][ni][r] + bv[ni];
    }
  }
}

__global__ __launch_bounds__(512, 2) void gemm_all(
    const float* __restrict__ x, const char* __restrict__ zeros,
    const unsigned short* __restrict__ Wz,
    const int* __restrict__ counts, const int* __restrict__ idxb,
    const float* __restrict__ bias, float* __restrict__ out) {
  extern __shared__ char sm[];
  __shared__ int eidx[256];
  // Bijective XCD swizzle: all 80 blocks of system s land on XCD (s&7) ->
  // W panel and A-slabs stay L2/LLC-local across mt re-reads.
  // grid = 1280 = 8 xcd * 160; per XCD: systems (xcd) then (xcd+8), bx fastest.
  int g = blockIdx.x;
  int xcd = g & 7, j = g >> 3;          // j in 0..159
  int s = xcd + 8 * (j / 80);
  int r = j % 80;
  int mt = r / 10, bx = r % 10;         // mt: 8 x 256-row tiles; bx: 3+4+3 col-pairs
  if (bx < 3)      gemm_body<0>(x, zeros, Wz, counts, idxb, bias, out, s, mt, bx,     sm, eidx);
  else if (bx < 7) gemm_body<1>(x, zeros, Wz, counts, idxb, bias, out, s, mt, bx - 3, sm, eidx);
  else             gemm_body<2>(x, zeros, Wz, counts, idxb, bias, out, s, mt, bx - 7, sm, eidx);
}

extern "C" void kernel_launch(void* const* d_in, const int* in_sizes, int n_in,
                              void* d_out, int out_size, void* d_ws, size_t ws_size,
                              hipStream_t stream) {
  const float* x  = (const float*)d_in[0];
  // d_in[1] = x_edge: unused by the reference
  const float* ce = (const float*)d_in[2];
  const int*   eb = (const int*)d_in[3];
  const float* W0 = (const float*)d_in[4];
  const float* b0 = (const float*)d_in[5];
  const float* W1 = (const float*)d_in[6];
  const float* W2 = (const float*)d_in[7];
  float* out = (float*)d_out;
  char* ws = (char*)d_ws;
  int*   counts = (int*)ws;
  char*  zeros  = ws + 256;                      // zeroed by the memset below
  int*   idxb   = (int*)(ws + WS_IDX_OFF);
  float* bias   = (float*)(ws + WS_BIAS_OFF);
  unsigned short* Wz = (unsigned short*)(ws + WS_W_OFF);

  hipMemsetAsync(ws, 0, 1024, stream);           // counts + zeros region
  bucket_kernel<<<48, 256, 0, stream>>>(eb, counts, idxb);
  bias_kernel<<<40, 256, 0, stream>>>(ce, b0, bias);
  mix_all<<<1000, 256, 0, stream>>>(W0, W1, W2, ce, Wz);
  gemm_all<<<1280, 512, 81920, stream>>>(x, zeros, Wz, counts, idxb, bias, out);
}

// Round 6
// 324.998 us; speedup vs baseline: 1.0229x; 1.0229x over previous
//
#include <hip/hip_runtime.h>
#include <cstdint>

#define N_EDGES 12288
#define ROWLEN  2432      // 19*128 floats per edge
#define CAP     2048      // per-system bucket capacity (buckets avg 768)

typedef __bf16 bf16;
typedef __bf16 bf16x8 __attribute__((ext_vector_type(8)));
typedef __bf16 bf16x4 __attribute__((ext_vector_type(4)));
typedef float  f32x4  __attribute__((ext_vector_type(4)));

#define ELEMS0 (640*640)
#define ELEMS1 (1024*1024)
#define ELEMS2 (768*768)

// ws byte offsets (no xb buffer: A is cast f32->bf16 inside the GEMM)
#define WS_IDX_OFF   1024
#define WS_BIAS_OFF  (WS_IDX_OFF + 16*CAP*4)                 // 132096
#define WS_W_OFF     (WS_BIAS_OFF + 16*640*4)                // 173056
#define WZ_ELEMS     ((size_t)16*(ELEMS0+ELEMS1+ELEMS2))     // 32.77M bf16

// After the SO(2) "hat" fold every branch is a square GEMM with K == N.
template<int B> struct Cfg;
template<> struct Cfg<0> { static constexpr int K=640,  KS=640, XOFF=0,    NT=5;
                           static constexpr size_t WOFF=0; };
template<> struct Cfg<1> { static constexpr int K=1024, KS=512, XOFF=640,  NT=8;
                           static constexpr size_t WOFF=(size_t)16*ELEMS0; };
template<> struct Cfg<2> { static constexpr int K=768,  KS=384, XOFF=1664, NT=6;
                           static constexpr size_t WOFF=(size_t)16*ELEMS0+(size_t)16*ELEMS1; };

__device__ __forceinline__ void async_copy16(const void* g, void* l) {
  // global -> LDS direct copy, 16B/lane; LDS dest = wave-uniform base + lane*16.
  auto gp = reinterpret_cast<const __attribute__((address_space(1))) unsigned int*>(
      reinterpret_cast<uintptr_t>(g));
  auto lp = reinterpret_cast<__attribute__((address_space(3))) unsigned int*>(
      (unsigned int)reinterpret_cast<uintptr_t>(l));
  __builtin_amdgcn_global_load_lds(gp, lp, 16, 0, 0);
}

// ---------------- bucketing: LDS histogram, 16 global atomics per block ------
__global__ void bucket_kernel(const int* __restrict__ eb, int* __restrict__ counts,
                              int* __restrict__ idxb) {
  __shared__ int hcnt[16], hbase[16];
  int tid = threadIdx.x;
  int t = blockIdx.x * 256 + tid;
  if (tid < 16) hcnt[tid] = 0;
  __syncthreads();
  int s = -1, lp = 0;
  if (t < N_EDGES) { s = eb[t]; lp = atomicAdd(&hcnt[s], 1); }
  __syncthreads();
  if (tid < 16) hbase[tid] = atomicAdd(counts + tid, hcnt[tid]);
  __syncthreads();
  if (s >= 0) { int p = hbase[s] + lp; if (p < CAP) idxb[s * CAP + p] = t; }
}

// ---------------- mixed bias ----------------
__global__ void bias_kernel(const float* __restrict__ ce, const float* __restrict__ b0,
                            float* __restrict__ bias) {
  int t = blockIdx.x * 256 + threadIdx.x;   // 0..10239
  int s = t / 640, c = t - s * 640;
  float a = 0.f;
#pragma unroll
  for (int e = 0; e < 8; ++e) a += ce[s * 8 + e] * b0[e * 640 + c];
  bias[t] = a;
}

// ---------------- weight mixing + hat fold + swizzle + bf16 cast ----------------
// dst layout per (branch, system): [kblk][chunk128][kgrp:4][n:128][k8:8] bf16.
template<int B>
__device__ __forceinline__ void mix_body(const float* __restrict__ Wsrc,
                                         const float* ce_s,
                                         unsigned short* __restrict__ Wz, int pos) {
  constexpr int N = Cfg<B>::K, KS = Cfg<B>::KS, NT = N / 128, HALF = N / 2;
  constexpr int SRC_STRIDE = KS * N;
  constexpr size_t DST_STRIDE = (size_t)Cfg<B>::K * N;
  int nn = pos & 127, kgrp = (pos >> 7) & 3, rest = pos >> 9;
  int nt = rest % NT, kblk = rest / NT;
  int i0 = kblk * 32 + kgrp * 8;
  int c  = nt * 128 + nn;
  int si = i0, sc = c; float sg = 1.f;
  if (B > 0 && i0 >= KS) {                      // lower half of hat: [-W2 | W1]
    si = i0 - KS;
    if (c < HALF) { sc = c + HALF; sg = -1.f; } else { sc = c - HALF; }
  }
  float w[8][8];
  const float* p0 = Wsrc + (size_t)si * N + sc;
#pragma unroll
  for (int e = 0; e < 8; ++e) {
    const float* p = p0 + (size_t)e * SRC_STRIDE;
#pragma unroll
    for (int j = 0; j < 8; ++j)
      w[e][j] = sg * p[(size_t)j * N];   // plain loads: hat-fold re-read hits LLC
  }
  unsigned short* db = Wz + Cfg<B>::WOFF + (size_t)pos * 8;
#pragma unroll
  for (int s = 0; s < 16; ++s) {
    float a[8] = {0, 0, 0, 0, 0, 0, 0, 0};
#pragma unroll
    for (int e = 0; e < 8; ++e) {
      float cc = ce_s[s * 8 + e];
#pragma unroll
      for (int j = 0; j < 8; ++j) a[j] += cc * w[e][j];
    }
    bf16x8 v;
#pragma unroll
    for (int j = 0; j < 8; ++j) v[j] = (bf16)a[j];
    *(bf16x8*)(db + s * DST_STRIDE) = v;
  }
}

__global__ __launch_bounds__(256) void mix_all(const float* __restrict__ W0,
                                               const float* __restrict__ W1,
                                               const float* __restrict__ W2,
                                               const float* __restrict__ ce,
                                               unsigned short* __restrict__ Wz) {
  __shared__ float ce_s[128];
  int tid = threadIdx.x;
  if (tid < 128) ce_s[tid] = ce[tid];
  __syncthreads();
  int bx = blockIdx.x;
  if (bx < 200)      mix_body<0>(W0, ce_s, Wz, bx * 256 + tid);
  else if (bx < 712) mix_body<1>(W1, ce_s, Wz, (bx - 200) * 256 + tid);
  else               mix_body<2>(W2, ce_s, Wz, (bx - 712) * 256 + tid);
}

// ---------------- grouped GEMM: 128x256 tile, 4 waves, counted-vmcnt pipeline -
// A staging is FULL-LINE: 8 threads/row x 16 contiguous bytes. Each wave-instr
// covers 8 rows x 128 B = 8 complete cache lines -> 128 line-requests per
// block-step (was 512 partial-line requests: 2 lanes x 16 B strided per row per
// instr = every row's line requested 4x with 32 B used). TA request rate
// (~1/cyc/CU) was the schedule-invariant cost that three different schedules
// (rounds 3/4/5, all ~130-144 us, MfmaUtil ~16.5%) could not move.
// LDS A-write: 4x ds_write_b64 with kq-XOR swizzle (slot = row ^ (kq<<1)):
// verified conflict-free across a quarter-wave (all 32 banks distinct);
// af reads apply the same XOR (permutation within each aligned 16-row group).
template<int B>
__device__ __forceinline__ void gemm_body(
    const float* __restrict__ x, const char* __restrict__ zeros,
    const unsigned short* __restrict__ Wz,
    const int* __restrict__ counts, const int* __restrict__ idxb,
    const float* __restrict__ bias, float* __restrict__ out,
    int s, int mt, int nt2, char* sm, int* eidx)
{
  constexpr int K = Cfg<B>::K, NT = Cfg<B>::NT, KB = K / 32, XOFF = Cfg<B>::XOFF;
  int cnt = counts[s];
  int m0 = mt * 128;
  if (m0 >= cnt) return;
  int tid = threadIdx.x;
  if (tid < 128) eidx[tid] = (m0 + tid < cnt) ? idxb[s * CAP + m0 + tid] : -1;
  __syncthreads();
  // LDS: A bufs 2x8KB ([kq:4][row:128] 16B slots, row XOR-swizzled), B 3x16KB.
  char* Acur = sm;          char* Anxt = sm + 8192;
  char* Bc = sm + 16384;    char* Bm = sm + 32768;    char* Bn = sm + 49152;
  int wv = tid >> 6, ln = tid & 63;
  int wm = wv >> 1, wn = wv & 1;          // 2m x 2n waves, each owns 64x128 output
  int kq = ln >> 4, lm = ln & 15;
  int c0 = nt2 * 2;
  // A source: 8 threads/row; c16 = k-chunk (16 B of f32 = 4 k values).
  // Thread covers rows rbase + 32*i, i = 0..3.
  int c16 = tid & 7, rbase = tid >> 3;    // rbase 0..31
  int kq_w = c16 >> 1, half = c16 & 1;    // dest plane + 8B half of 16B chunk
  const char* arow4[4]; int kinc4[4];
#pragma unroll
  for (int i = 0; i < 4; ++i) {
    int e = eidx[rbase + 32 * i];
    if (e >= 0) { arow4[i] = (const char*)(x + (size_t)e * ROWLEN + XOFF); kinc4[i] = 128; }
    else        { arow4[i] = zeros; kinc4[i] = 0; }
  }
  const unsigned short* wb = Wz + Cfg<B>::WOFF + (size_t)s * K * K;

  f32x4 sreg[4];                                   // staged A (4 rows x 4 f32)
  auto loadA = [&](int kb) {                       // issue early (T14 split)
#pragma unroll
    for (int i = 0; i < 4; ++i)
      sreg[i] = *(const f32x4*)(arow4[i] + (size_t)kb * kinc4[i] + c16 * 16);
  };
  auto writeA = [&](char* dst) {                   // cvt + swizzled ds_write_b64
#pragma unroll
    for (int i = 0; i < 4; ++i) {
      int r = rbase + 32 * i;
      bf16x4 v;
      v[0] = (bf16)sreg[i][0]; v[1] = (bf16)sreg[i][1];
      v[2] = (bf16)sreg[i][2]; v[3] = (bf16)sreg[i][3];
      *(bf16x4*)(dst + kq_w * 2048 + ((r ^ (kq_w << 1)) * 16) + half * 8) = v;
    }
  };
  auto stageB = [&](int kb, char* dst) {
    const unsigned short* base = wb + (size_t)kb * (NT * 4096);
#pragma unroll
    for (int i = 0; i < 4; ++i) {
      int c = i * 256 + tid;                       // 1024 16B chunks per buf
      int ck = c0 + (c >> 9); if (ck > NT - 1) ck = NT - 1;   // clamp (dup, discarded)
      async_copy16(base + (size_t)ck * 4096 + (c & 511) * 8,
                   dst + (i * 256 + wv * 64) * 16);
    }
  };

  f32x4 acc[4][8];
#pragma unroll
  for (int i = 0; i < 4; ++i)
#pragma unroll
    for (int j = 0; j < 8; ++j) {
      acc[i][j][0] = 0.f; acc[i][j][1] = 0.f; acc[i][j][2] = 0.f; acc[i][j][3] = 0.f;
    }

  // Prologue: Acur = A(0) written, Bc = B(0) landed, Bm = B(1) + sreg = A(1)
  // in flight. In-loop we never drain vmcnt(0); loads stay in flight across
  // the raw s_barriers (counted waits are compiler-generated via sreg use).
  loadA(0);
  stageB(0, Bc);
  writeA(Acur);                // compiler waits vmcnt for sreg, then ds_writes
  asm volatile("s_waitcnt vmcnt(0)" ::: "memory");   // B(0) landed (one-time drain)
  stageB(1, Bm);
  loadA(1);
  asm volatile("s_waitcnt lgkmcnt(0)" ::: "memory"); // own A(0) ds_writes done
  __builtin_amdgcn_s_barrier();
  __builtin_amdgcn_sched_barrier(0);

#pragma unroll 1
  for (int kb = 0; kb < KB; ++kb) {
    if (kb + 2 < KB) stageB(kb + 2, Bn);          // prefetch depth-2
    bf16x8 af[4], bq[8];
#pragma unroll
    for (int mi = 0; mi < 4; ++mi) {
      int r = wm * 64 + mi * 16 + lm;
      af[mi] = *(const bf16x8*)(Acur + kq * 2048 + ((r ^ (kq << 1)) * 16));
    }
#pragma unroll
    for (int ni = 0; ni < 8; ++ni)
      bq[ni] = *(const bf16x8*)(Bc + wn * 8192 + kq * 2048 + (ni * 16 + lm) * 16);
    __builtin_amdgcn_s_setprio(1);
#pragma unroll
    for (int mi = 0; mi < 4; ++mi)
#pragma unroll
      for (int ni = 0; ni < 8; ++ni)
        acc[mi][ni] = __builtin_amdgcn_mfma_f32_16x16x32_bf16(af[mi], bq[ni], acc[mi][ni], 0, 0, 0);
    __builtin_amdgcn_s_setprio(0);
    if (kb + 1 < KB) {
      writeA(Anxt);            // auto vmcnt wait retires loadA(kb+1) AND B(kb+1)
      if (kb + 2 < KB) loadA(kb + 2);             // refill sreg for next writeA
    }
    asm volatile("s_waitcnt lgkmcnt(0)" ::: "memory");  // own ds_writes visible
    __builtin_amdgcn_s_barrier();                 // raw: vmcnt stays nonzero
    __builtin_amdgcn_sched_barrier(0);
    char* t = Acur; Acur = Anxt; Anxt = t;        // rotate buffers
    char* tb = Bc; Bc = Bm; Bm = Bn; Bn = tb;
  }
  // epilogue: C/D layout col=lane&15, row=(lane>>4)*4+reg
  int cc = c0 + wn;
  if (cc >= NT) return;
  float bv[8] = {0, 0, 0, 0, 0, 0, 0, 0};
  if (B == 0) {
#pragma unroll
    for (int ni = 0; ni < 8; ++ni)
      bv[ni] = bias[s * 640 + cc * 128 + ni * 16 + lm];
  }
#pragma unroll
  for (int mi = 0; mi < 4; ++mi) {
#pragma unroll
    for (int r = 0; r < 4; ++r) {
      int row = wm * 64 + mi * 16 + kq * 4 + r;
      int e = eidx[row];
      if (e < 0) continue;
      float* po = out + (size_t)e * ROWLEN + XOFF + cc * 128 + lm;
#pragma unroll
      for (int ni = 0; ni < 8; ++ni) po[ni * 16] = acc[mi][ni][r] + bv[ni];
    }
  }
}

__global__ __launch_bounds__(256, 2) void gemm_all(
    const float* __restrict__ x, const char* __restrict__ zeros,
    const unsigned short* __restrict__ Wz,
    const int* __restrict__ counts, const int* __restrict__ idxb,
    const float* __restrict__ bias, float* __restrict__ out) {
  extern __shared__ char sm[];
  __shared__ int eidx[128];
  // Bijective XCD swizzle: all 160 blocks of system s land on XCD (s&7) ->
  // W panel and A-slabs stay L2/LLC-local across mt re-reads.
  // grid = 2560 = 8 xcd * 320; per XCD: systems (xcd) then (xcd+8), bx fastest.
  int g = blockIdx.x;
  int xcd = g & 7, j = g >> 3;          // j in 0..319
  int s = xcd + 8 * (j / 160);
  int r = j % 160;
  int mt = r / 10, bx = r % 10;         // mt: 16 x 128-row tiles; bx: 3+4+3 col-pairs
  if (bx < 3)      gemm_body<0>(x, zeros, Wz, counts, idxb, bias, out, s, mt, bx,     sm, eidx);
  else if (bx < 7) gemm_body<1>(x, zeros, Wz, counts, idxb, bias, out, s, mt, bx - 3, sm, eidx);
  else             gemm_body<2>(x, zeros, Wz, counts, idxb, bias, out, s, mt, bx - 7, sm, eidx);
}

extern "C" void kernel_launch(void* const* d_in, const int* in_sizes, int n_in,
                              void* d_out, int out_size, void* d_ws, size_t ws_size,
                              hipStream_t stream) {
  const float* x  = (const float*)d_in[0];
  // d_in[1] = x_edge: unused by the reference
  const float* ce = (const float*)d_in[2];
  const int*   eb = (const int*)d_in[3];
  const float* W0 = (const float*)d_in[4];
  const float* b0 = (const float*)d_in[5];
  const float* W1 = (const float*)d_in[6];
  const float* W2 = (const float*)d_in[7];
  float* out = (float*)d_out;
  char* ws = (char*)d_ws;
  int*   counts = (int*)ws;
  char*  zeros  = ws + 256;                      // zeroed by the memset below
  int*   idxb   = (int*)(ws + WS_IDX_OFF);
  float* bias   = (float*)(ws + WS_BIAS_OFF);
  unsigned short* Wz = (unsigned short*)(ws + WS_W_OFF);

  hipMemsetAsync(ws, 0, 1024, stream);           // counts + zeros region
  bucket_kernel<<<48, 256, 0, stream>>>(eb, counts, idxb);
  bias_kernel<<<40, 256, 0, stream>>>(ce, b0, bias);
  mix_all<<<1000, 256, 0, stream>>>(W0, W1, W2, ce, Wz);
  gemm_all<<<2560, 256, 65536, stream>>>(x, zeros, Wz, counts, idxb, bias, out);
}